// Round 9
// baseline (941.565 us; speedup 1.0000x reference)
//
#include <hip/hip_runtime.h>
#include <hip/hip_bf16.h>

#define BB 128
#define TT 512
#define EE 128
#define HH 256
#define MM 1024
#define CC 5

typedef _Float16 h2 __attribute__((ext_vector_type(2)));
typedef __fp16 f16x8 __attribute__((ext_vector_type(8)));
typedef __fp16 f16x2 __attribute__((ext_vector_type(2)));
typedef float  f32x4 __attribute__((ext_vector_type(4)));

struct alignas(8) H4 { h2 a, b; };      // 4 f16 = 8B

__device__ inline h2 mkh2(float a, float b) {
    return __builtin_bit_cast(h2, __builtin_amdgcn_cvt_pkrtz(a, b));
}

__device__ inline f16x8 pack8(float4 lo, float4 hi) {
    union { f16x2 h[4]; f16x8 v; } u;
    u.h[0] = __builtin_amdgcn_cvt_pkrtz(lo.x, lo.y);
    u.h[1] = __builtin_amdgcn_cvt_pkrtz(lo.z, lo.w);
    u.h[2] = __builtin_amdgcn_cvt_pkrtz(hi.x, hi.y);
    u.h[3] = __builtin_amdgcn_cvt_pkrtz(hi.z, hi.w);
    return u.v;
}

__device__ inline float fast_tanh(float x) {
    float e = __expf(2.0f * x);
    return 1.0f - 2.0f / (e + 1.0f);
}

// ---------------------------------------------------------------------------
// K1 (MFMA GEMM): u[b][ch][t] = bias[ch] + emb[x[b*T+t]] @ W_ih^T  (f16).
// NOTE output layout is now t-MINOR (transposed) so k_rnn can register-stash
// 8 consecutive steps per b128. D rows (quad*4+reg) are 4 consecutive t ->
// store b64 straight from the accumulators; no LDS epilogue.
// Layouts (R7-verified on HW): A[m=lane&15][k=quad*8+j],
// B[k=quad*8+j][n=lane&15], D col=lane&15 row=quad*4+reg.
// ---------------------------------------------------------------------------
__global__ __launch_bounds__(256, 2)
void k_embed(const int* __restrict__ x,
             const float* __restrict__ emb, const float* __restrict__ W_ih,
             const float* __restrict__ b_ih, const float* __restrict__ b_hh,
             _Float16* __restrict__ u)
{
    const int tb   = blockIdx.x;          // 32-token tile (within one batch)
    const int tid  = threadIdx.x;
    const int wv   = tid >> 6;
    const int lane = tid & 63;
    const int l15  = lane & 15;
    const int quad = lane >> 4;

    __shared__ __align__(16) char lds[32 * 256];   // A-stage: 32 rows x 128 f16

    // B fragments: B[k][n] = W_ih[n][k]; n = 64*wv + 16*ct + l15
    f16x8 bf[4][4];
    float bias[4];
    #pragma unroll
    for (int ct = 0; ct < 4; ++ct) {
        const int n = 64 * wv + 16 * ct + l15;
        const float* wp = W_ih + (size_t)n * EE;
        #pragma unroll
        for (int kc = 0; kc < 4; ++kc) {
            const float4* p = (const float4*)(wp + 32 * kc + 8 * quad);
            bf[ct][kc] = pack8(p[0], p[1]);
        }
        bias[ct] = b_ih[n] + b_hh[n];
    }

    // gather 32 emb rows -> f16 LDS A[32][128]
    {
        const int r = tid >> 3;
        const int s = tid & 7;
        const int tok = x[tb * 32 + r];
        const float4* ep = (const float4*)(emb + (size_t)tok * EE + 16 * s);
        float4 a = ep[0], b = ep[1], c = ep[2], d = ep[3];
        *(f16x8*)(lds + r * 256 + 32 * s)      = pack8(a, b);
        *(f16x8*)(lds + r * 256 + 32 * s + 16) = pack8(c, d);
    }
    __syncthreads();

    f32x4 acc[2][4];
    #pragma unroll
    for (int rt = 0; rt < 2; ++rt)
        #pragma unroll
        for (int ct = 0; ct < 4; ++ct)
            acc[rt][ct] = (f32x4){bias[ct], bias[ct], bias[ct], bias[ct]};

    #pragma unroll
    for (int kc = 0; kc < 4; ++kc) {
        const int ko = (32 * kc + 8 * quad) * 2;
        f16x8 a0 = *(const f16x8*)(lds + (l15)      * 256 + ko);
        f16x8 a1 = *(const f16x8*)(lds + (16 + l15) * 256 + ko);
        #pragma unroll
        for (int ct = 0; ct < 4; ++ct) {
            acc[0][ct] = __builtin_amdgcn_mfma_f32_16x16x32_f16(a0, bf[ct][kc], acc[0][ct], 0, 0, 0);
            acc[1][ct] = __builtin_amdgcn_mfma_f32_16x16x32_f16(a1, bf[ct][kc], acc[1][ct], 0, 0, 0);
        }
    }

    // store: u[b][ch][t]: rows of D are consecutive t -> b64 per (rt,ct)
    const int bb  = tb >> 4;               // batch
    const int tt0 = (tb & 15) * 32;        // tile's first t
    #pragma unroll
    for (int rt = 0; rt < 2; ++rt) {
        #pragma unroll
        for (int ct = 0; ct < 4; ++ct) {
            const int ch   = 64 * wv + 16 * ct + l15;
            const int tloc = tt0 + 16 * rt + 4 * quad;
            H4 o;
            o.a = mkh2(acc[rt][ct][0], acc[rt][ct][1]);
            o.b = mkh2(acc[rt][ct][2], acc[rt][ct][3]);
            *(H4*)((char*)u + ((size_t)(bb * HH + ch) * TT + tloc) * 2) = o;
        }
    }
}

// ---------------------------------------------------------------------------
// K2 (MFMA scan): 16 chains per WG (8 WGs), 256 thr.  Per step:
//   D[out_ch][chain] = W_hh (A, in 128 regs/lane) x h^T (B, from LDS).
// Wave wv owns out_ch [64wv,64wv+64) = 4 M-tiles; B-frags (8 x b128) are
// shared across M-tiles. acc C-init = u_t (register-stashed 8 steps ahead
// from the t-minor u layout). tanh + per-chain activity mask; h_new packed
// to f16 and written b64 to the alternate h buffer (xor-16B swizzle vs the
// chain index kills same-bank pathology). 1 barrier/step; no global loads
// between barriers except the once-per-8-steps stash refill.
// ---------------------------------------------------------------------------
__global__ __launch_bounds__(256, 1)
void k_rnn(const int* __restrict__ lengths, const float* __restrict__ W_hh,
           const _Float16* __restrict__ u, float* __restrict__ hn)
{
    const int b0   = blockIdx.x * 16;
    const int tid  = threadIdx.x;
    const int wv   = tid >> 6;
    const int lane = tid & 63;
    const int l15  = lane & 15;
    const int q    = lane >> 4;

    __shared__ __align__(16) char lds[2 * 8192];   // h double buffer, swizzled

    // A = W_hh fragments, loaded once: A[m=l15][k=q*8+j] per (Mtile,Kfrag)
    f16x8 A[4][8];
    #pragma unroll
    for (int mt = 0; mt < 4; ++mt) {
        const float* wr = W_hh + (size_t)(wv * 64 + mt * 16 + l15) * HH;
        #pragma unroll
        for (int kf = 0; kf < 8; ++kf) {
            const float4* p = (const float4*)(wr + kf * 32 + q * 8);
            A[mt][kf] = pack8(p[0], p[1]);
        }
    }

    const int t0v = TT - lengths[b0 + l15];   // chain l15 active iff t >= t0v

    // u base pointers: lane's (chain=l15, out_ch = wv*64+mt*16+q*4+r), t-minor
    const char* up[4];
    #pragma unroll
    for (int mt = 0; mt < 4; ++mt)
        up[mt] = (const char*)u
               + ((size_t)(b0 + l15) * HH + wv * 64 + mt * 16 + q * 4) * (TT * 2);

    // swizzled LDS offsets: byte of (chain, ch_byte) = chain*512 + ((ch_byte + chain*16)&511)
    int roff[8], woff[4];
    #pragma unroll
    for (int kf = 0; kf < 8; ++kf)
        roff[kf] = l15 * 512 + ((kf * 64 + q * 16 + l15 * 16) & 511);
    #pragma unroll
    for (int mt = 0; mt < 4; ++mt)
        woff[mt] = l15 * 512 + ((wv * 128 + mt * 32 + q * 8 + l15 * 16) & 511);

    {   // zero both h buffers (16 KB)
        float4 z = {0.f, 0.f, 0.f, 0.f};
        #pragma unroll
        for (int i = 0; i < 4; ++i) *(float4*)(lds + tid * 16 + i * 4096) = z;
    }
    __syncthreads();

    f16x8 sA[16], sB[16];

#define LOADC(SX)                                                         \
    { _Pragma("unroll")                                                   \
      for (int i = 0; i < 16; ++i)                                        \
          SX[i] = *(const f16x8*)(up[i >> 2] + (i & 3) * (TT * 2));       \
      _Pragma("unroll")                                                   \
      for (int mt = 0; mt < 4; ++mt) up[mt] += 16; }

#define DO8(SX, TBASE)                                                    \
    { _Pragma("unroll")                                                   \
      for (int s = 0; s < 8; ++s) {                                       \
        f32x4 ac0 = {(float)SX[0][s], (float)SX[1][s],                    \
                     (float)SX[2][s], (float)SX[3][s]};                   \
        f32x4 ac1 = {(float)SX[4][s], (float)SX[5][s],                    \
                     (float)SX[6][s], (float)SX[7][s]};                   \
        f32x4 ac2 = {(float)SX[8][s], (float)SX[9][s],                    \
                     (float)SX[10][s], (float)SX[11][s]};                 \
        f32x4 ac3 = {(float)SX[12][s], (float)SX[13][s],                  \
                     (float)SX[14][s], (float)SX[15][s]};                 \
        const int rdo = (s & 1) ? 8192 : 0;                               \
        _Pragma("unroll")                                                 \
        for (int kf = 0; kf < 8; ++kf) {                                  \
            f16x8 bfr = *(const f16x8*)(lds + rdo + roff[kf]);            \
            ac0 = __builtin_amdgcn_mfma_f32_16x16x32_f16(A[0][kf], bfr, ac0, 0, 0, 0); \
            ac1 = __builtin_amdgcn_mfma_f32_16x16x32_f16(A[1][kf], bfr, ac1, 0, 0, 0); \
            ac2 = __builtin_amdgcn_mfma_f32_16x16x32_f16(A[2][kf], bfr, ac2, 0, 0, 0); \
            ac3 = __builtin_amdgcn_mfma_f32_16x16x32_f16(A[3][kf], bfr, ac3, 0, 0, 0); \
        }                                                                 \
        const bool act = ((TBASE) + s >= t0v);                            \
        const int wro = (s & 1) ? 0 : 8192;                               \
        f32x4* accs[4] = {&ac0, &ac1, &ac2, &ac3};                        \
        _Pragma("unroll")                                                 \
        for (int mt = 0; mt < 4; ++mt) {                                  \
            f32x4 a = *accs[mt];                                          \
            float v0 = act ? fast_tanh(a[0]) : 0.f;                       \
            float v1 = act ? fast_tanh(a[1]) : 0.f;                       \
            float v2 = act ? fast_tanh(a[2]) : 0.f;                       \
            float v3 = act ? fast_tanh(a[3]) : 0.f;                       \
            H4 o; o.a = mkh2(v0, v1); o.b = mkh2(v2, v3);                 \
            *(H4*)(lds + wro + woff[mt]) = o;                             \
        }                                                                 \
        __syncthreads();                                                  \
      } }

    LOADC(sA);                       // chunk 0
    for (int c2 = 0; c2 < 32; ++c2) {
        LOADC(sB);                   // chunk 2*c2+1 (in flight over DO8)
        DO8(sA, c2 * 16);
        if (c2 < 31) LOADC(sA);      // chunk 2*c2+2
        DO8(sB, c2 * 16 + 8);
    }
#undef DO8
#undef LOADC

    // final h is in buffer 0 (512 steps = even #flips); write hn as f32
    #pragma unroll
    for (int mt = 0; mt < 4; ++mt) {
        H4 hv = *(const H4*)(lds + woff[mt]);
        float4 o;
        o.x = (float)hv.a.x; o.y = (float)hv.a.y;
        o.z = (float)hv.b.x; o.w = (float)hv.b.y;
        *(float4*)(hn + (size_t)(b0 + l15) * HH + wv * 64 + mt * 16 + q * 4) = o;
    }
}

// ---------------------------------------------------------------------------
// K3: MLP head + log_softmax. One block per batch row. (unchanged)
// ---------------------------------------------------------------------------
__global__ __launch_bounds__(256, 2)
void k_head(const float* __restrict__ hn, const float* __restrict__ W0,
            const float* __restrict__ b0, const float* __restrict__ W1,
            const float* __restrict__ b1, float* __restrict__ out)
{
    const int b = blockIdx.x;
    const int tid = threadIdx.x;
    __shared__ float sh[HH];
    __shared__ float sh1[MM];
    __shared__ float sred[CC][4];
    __shared__ float slog[CC];

    sh[tid] = hn[(size_t)b * HH + tid];
    __syncthreads();

    float acc[4];
    #pragma unroll
    for (int i = 0; i < 4; ++i) acc[i] = b0[tid + 256 * i];
    const float4* sh4 = (const float4*)sh;
    for (int k4 = 0; k4 < HH / 4; ++k4) {
        float4 hv = sh4[k4];
        #pragma unroll
        for (int i = 0; i < 4; ++i) {
            float4 wv = ((const float4*)(W0 + (size_t)(tid + 256 * i) * HH))[k4];
            acc[i] += wv.x * hv.x + wv.y * hv.y + wv.z * hv.z + wv.w * hv.w;
        }
    }
    #pragma unroll
    for (int i = 0; i < 4; ++i) sh1[tid + 256 * i] = fmaxf(acc[i], 0.f);
    __syncthreads();

    float pc[CC] = {0.f, 0.f, 0.f, 0.f, 0.f};
    for (int k = tid; k < MM; k += 256) {
        float hv = sh1[k];
        #pragma unroll
        for (int c = 0; c < CC; ++c) pc[c] += W1[(size_t)c * MM + k] * hv;
    }
    const int lane = tid & 63, wid = tid >> 6;
    #pragma unroll
    for (int c = 0; c < CC; ++c) {
        float v = pc[c];
        #pragma unroll
        for (int off = 32; off > 0; off >>= 1) v += __shfl_down(v, off, 64);
        if (lane == 0) sred[c][wid] = v;
    }
    __syncthreads();
    if (tid < CC) {
        float s = sred[tid][0] + sred[tid][1] + sred[tid][2] + sred[tid][3]
                + b1[tid];
        slog[tid] = fmaxf(s, 0.f);
    }
    __syncthreads();
    if (tid < CC) {
        float mx = slog[0];
        #pragma unroll
        for (int c = 1; c < CC; ++c) mx = fmaxf(mx, slog[c]);
        float se = 0.f;
        #pragma unroll
        for (int c = 0; c < CC; ++c) se += __expf(slog[c] - mx);
        out[(size_t)b * CC + tid] = slog[tid] - mx - __logf(se);
    }
}

// ---------------------------------------------------------------------------
extern "C" void kernel_launch(void* const* d_in, const int* in_sizes, int n_in,
                              void* d_out, int out_size, void* d_ws, size_t ws_size,
                              hipStream_t stream) {
    const int*   x       = (const int*)d_in[0];
    const int*   lengths = (const int*)d_in[1];
    const float* emb     = (const float*)d_in[2];
    const float* W_ih    = (const float*)d_in[3];
    const float* W_hh    = (const float*)d_in[4];
    const float* b_ih    = (const float*)d_in[5];
    const float* b_hh    = (const float*)d_in[6];
    const float* W0      = (const float*)d_in[7];
    const float* b0      = (const float*)d_in[8];
    const float* W1      = (const float*)d_in[9];
    const float* b1      = (const float*)d_in[10];
    float* out = (float*)d_out;

    _Float16* u  = (_Float16*)d_ws;                       // [B][H][T] f16
    float*    hn = (float*)((char*)d_ws + (size_t)BB * TT * HH * sizeof(_Float16));

    k_embed<<<(BB * TT) / 32, 256, 0, stream>>>(x, emb, W_ih, b_ih, b_hh, u);
    k_rnn  <<<BB / 16, 256, 0, stream>>>(lengths, W_hh, u, hn);
    k_head <<<BB, 256, 0, stream>>>(hn, W0, b0, W1, b1, out);
}